// Round 10
// baseline (179.629 us; speedup 1.0000x reference)
//
#include <hip/hip_runtime.h>
#include <cstdint>

#define N 8192
#define NT 128     // 64-col chunks per row (N/64)
#define RITERS 12  // internal chaotic-relaxation iterations (correctness-free)
typedef unsigned long long u64;
typedef unsigned int u32;

__device__ inline u64 readlane64(u64 v, int lane) {
  u32 lo = (u32)__builtin_amdgcn_readlane((int)(u32)v, lane);
  u32 hi = (u32)__builtin_amdgcn_readlane((int)(u32)(v >> 32), lane);
  return ((u64)hi << 32) | lo;
}

// ---------------------------------------------------------------------------
// K1: sort keys (descending score, stable ascending index) + init aux + D,S=0
// ---------------------------------------------------------------------------
__global__ __launch_bounds__(256) void k_init(const float* __restrict__ scores,
                                              u64* __restrict__ keys,
                                              int* __restrict__ rank,
                                              int* __restrict__ cnt,
                                              float* __restrict__ prob,
                                              unsigned* __restrict__ y2m,
                                              int* __restrict__ first,
                                              u64* __restrict__ D,
                                              u64* __restrict__ S) {
  int i = blockIdx.x * 256 + threadIdx.x;
  if (i >= N) return;
  float sc = scores[i];
  keys[i] = ((u64)__float_as_uint(sc) << 32) | (unsigned)(0xFFFFFFFFu - (unsigned)i);
  rank[i] = 0;
  cnt[i] = 0;
  prob[i] = 0.0f;
  y2m[i] = 0u;
  first[i] = N;
  if (i < NT) { D[i] = 0ull; S[i] = 0ull; }
}

// ---------------------------------------------------------------------------
// K2: rank by counting (rank[i] = #{j : key[j] > key[i]}) -> stable descending
// ---------------------------------------------------------------------------
__global__ __launch_bounds__(256) void k_rank(const u64* __restrict__ keys,
                                              int* __restrict__ rank) {
  __shared__ u64 tile[1024];
  int e = blockIdx.x * 256 + threadIdx.x;
  int j0 = blockIdx.y * 1024;
  for (int t = threadIdx.x; t < 1024; t += 256) tile[t] = keys[j0 + t];
  __syncthreads();
  u64 ke = keys[e];
  int c = 0;
#pragma unroll 8
  for (int k = 0; k < 1024; ++k) c += (tile[k] > ke) ? 1 : 0;
  atomicAdd(&rank[e], c);
}

// ---------------------------------------------------------------------------
// K3: scatter into sorted SoA (clipped coords, score, area)
// ---------------------------------------------------------------------------
__global__ __launch_bounds__(256) void k_scatter(const float* __restrict__ boxes,
                                                 const float* __restrict__ scores,
                                                 const int* __restrict__ rank,
                                                 float* __restrict__ bx1s, float* __restrict__ by1s,
                                                 float* __restrict__ bx2s, float* __restrict__ by2s,
                                                 float* __restrict__ ss, float* __restrict__ areas) {
#pragma clang fp contract(off)
  int i = blockIdx.x * 256 + threadIdx.x;
  if (i >= N) return;
  int r = rank[i];
  float x1 = fminf(fmaxf(boxes[i * 4 + 0], 0.0f), 1920.0f);
  float y1 = fminf(fmaxf(boxes[i * 4 + 1], 0.0f), 1080.0f);
  float x2 = fminf(fmaxf(boxes[i * 4 + 2], 0.0f), 1920.0f);
  float y2 = fminf(fmaxf(boxes[i * 4 + 3], 0.0f), 1080.0f);
  bx1s[r] = x1; by1s[r] = y1; bx2s[r] = x2; by2s[r] = y2;
  ss[r] = scores[i];
  areas[r] = (x2 - x1 + 1.0f) * (y2 - y1 + 1.0f);
}

// ---------------------------------------------------------------------------
// K4: adjacency, SYMMETRIC lower-triangle, 4 tiles per 256-thread block
// (R9: 64-thr blocks ran at 40% occupancy; 4 waves/block lifts it). Band
// trick (R8, verified absmax 0.0): iou>0.5 <=> 2*inter>uni whenever
// |2*inter-uni| > 1e-6*uni; only in-band lanes take the exact IEEE divide.
// fp contract OFF; matrix float-exact symmetric; ballot transpose mirrors.
// ---------------------------------------------------------------------------
__global__ __launch_bounds__(256) void k_adj(const float* __restrict__ bx1s, const float* __restrict__ by1s,
                                             const float* __restrict__ bx2s, const float* __restrict__ by2s,
                                             const float* __restrict__ areas,
                                             u64* __restrict__ mtile,
                                             u64* __restrict__ mrow) {
#pragma clang fp contract(off)
  __shared__ float jx1[4][64], jy1[4][64], jx2[4][64], jy2[4][64], ja[4][64];
  int w = threadIdx.x >> 6, l = threadIdx.x & 63;
  int p = blockIdx.x * 4 + w;
  int gy = (int)((sqrtf(8.0f * (float)p + 1.0f) - 1.0f) * 0.5f);
  while ((gy + 1) * (gy + 2) / 2 <= p) ++gy;
  while (gy * (gy + 1) / 2 > p) --gy;
  int gx = p - gy * (gy + 1) / 2;

  int j = gx * 64 + l;
  jx1[w][l] = bx1s[j]; jy1[w][l] = by1s[j]; jx2[w][l] = bx2s[j]; jy2[w][l] = by2s[j]; ja[w][l] = areas[j];
  __syncthreads();
  int i = gy * 64 + l;
  float x1 = bx1s[i], y1 = by1s[i], x2 = bx2s[i], y2 = by2s[i], ai = areas[i];
  u64 bits = 0;
#pragma unroll 4
  for (int jj = 0; jj < 64; ++jj) {
    float ix1 = fmaxf(x1, jx1[w][jj]);
    float iy1 = fmaxf(y1, jy1[w][jj]);
    float ix2 = fminf(x2, jx2[w][jj]);
    float iy2 = fminf(y2, jy2[w][jj]);
    float iw = fmaxf(ix2 - ix1 + 1.0f, 0.0f);
    float ih = fmaxf(iy2 - iy1 + 1.0f, 0.0f);
    float inter = iw * ih;
    float uni = (ai + ja[w][jj]) - inter;   // uni > 0 always (areas >= 1)
    float t = inter + inter;                // exact (x2)
    bool gt = t > uni;
    bool amb = fabsf(t - uni) <= 1e-6f * uni;
    if (__ballot(amb) != 0ull) {            // ~never taken
      float iou = inter / uni;              // exact IEEE div, matches numpy
      if (amb) gt = iou > 0.5f;
    }
    bits |= ((u64)gt) << jj;
  }
  mtile[((size_t)gy * NT + gx) * 64 + l] = bits;
  mrow[(size_t)i * NT + gx] = bits;
  if (gx != gy) {
    u64 tb = 0;
#pragma unroll 8
    for (int c = 0; c < 64; ++c) {
      u64 wb = __ballot((bits >> c) & 1ull);
      tb = (l == c) ? wb : tb;
    }
    mtile[((size_t)gx * NT + gy) * 64 + l] = tb;
    mrow[(size_t)(gx * 64 + l) * NT + gy] = tb;
  }
}

// ---------------------------------------------------------------------------
// K5: FUSED classification (replaces 8 k_round launches). Block per tile gy,
// loops RITERS times over agent-scope views of D/S. Monotone-sound rules:
//   suppressed: some earlier neighbor in D
//   head:       ALL earlier neighbors in S
// Accelerator: anyE tracks EXTERNAL unknown earlier neighbors; when rE==0
// the tile's prefix is fully classified -> wave 0 runs the exact serial
// diagonal resolve (same invariant as k_fix) and completes the tile at once.
// Tiles complete as a sweep inside ONE launch. Staleness only delays.
// ---------------------------------------------------------------------------
__global__ __launch_bounds__(256) void k_rounds(const u64* __restrict__ mtile,
                                                u64* __restrict__ D,
                                                u64* __restrict__ S) {
  __shared__ u64 Dl[NT], Sl[NT];
  __shared__ u64 bw[3][4];
  __shared__ u64 fD, fU, fE;
  int gy = blockIdx.x;
  int t = threadIdx.x;
  int w = t >> 6, r = t & 63;
  u64 dAA = (w == 0) ? mtile[((size_t)gy * NT + gy) * 64 + r] : 0ull;

  for (int it = 0; it < RITERS; ++it) {
    if (t < NT) Dl[t] = __hip_atomic_load(&D[t], __ATOMIC_RELAXED, __HIP_MEMORY_SCOPE_AGENT);
    else Sl[t - NT] = __hip_atomic_load(&S[t - NT], __ATOMIC_RELAXED, __HIP_MEMORY_SCOPE_AGENT);
    __syncthreads();
    u64 classified = Dl[gy] | Sl[gy];
    if (classified == ~0ull) return;   // uniform: tile done
    bool unk = !((classified >> r) & 1ull);
    u64 anyD = 0, anyU = 0, anyE = 0;
    if (unk) {
      int k0 = 32 * w, k1 = min(k0 + 32, gy + 1);
      for (int k = k0; k < k1; ++k) {
        u64 m = mtile[((size_t)gy * NT + k) * 64 + r];
        if (k == gy) {
          m &= (1ull << r) - 1ull;       // strictly earlier within own tile
          anyD |= m & Dl[k];
          anyU |= m & ~Sl[k];
        } else {
          anyD |= m & Dl[k];
          anyU |= m & ~Sl[k];
          anyE |= m & ~(Sl[k] | Dl[k]);  // external unknown
        }
      }
    }
    u64 bD = __ballot(anyD != 0ull), bU = __ballot(anyU != 0ull), bE = __ballot(anyE != 0ull);
    if (r == 0) { bw[0][w] = bD; bw[1][w] = bU; bw[2][w] = bE; }
    __syncthreads();
    if (t == 0) {
      fD = bw[0][0] | bw[0][1] | bw[0][2] | bw[0][3];
      fU = bw[1][0] | bw[1][1] | bw[1][2] | bw[1][3];
      fE = bw[2][0] | bw[2][1] | bw[2][2] | bw[2][3];
    }
    __syncthreads();
    u64 rD = fD, rU = fU, rE = fE;
    u64 unkb = ~classified;
    if (rE == 0ull) {
      // exact in-tile resolve: prefix classified for every unknown row.
      // t0 rows have all external earlier neighbors in S and no known D
      // neighbor; ascending ctz chain == greedy NMS restricted to tile.
      if (w == 0) {
        u64 t0 = unkb & ~rD;
        u64 heads = 0, todo = t0;
        while (todo) {
          int i = __builtin_ctzll(todo);
          heads |= 1ull << i;
          todo &= ~readlane64(dAA, i);   // clears i (diag) + suppressed
        }
        if (r == 0) {
          if (heads) atomicOr(&D[gy], heads);
          u64 ns = unkb & ~heads;
          if (ns) atomicOr(&S[gy], ns);
        }
      }
      return;                            // uniform: all waves exit
    }
    if (t == 0) {
      u64 newS = unkb & rD;
      u64 newD = unkb & ~rD & ~rU;
      if (newS) atomicOr(&S[gy], newS);
      if (newD) atomicOr(&D[gy], newD);
    }
    __syncthreads();
  }
}

// ---------------------------------------------------------------------------
// K6: exact serial cleanup, ONE wave, branchless chain (R9). With k_rounds'
// resolve, M should be ~0; kept for unconditional correctness.
// ---------------------------------------------------------------------------
__global__ __launch_bounds__(64, 1) void k_fix(const u64* __restrict__ mrow,
                                               u64* __restrict__ D,
                                               const u64* __restrict__ S) {
  __shared__ int ulist[N];
  int l = threadIdx.x;
  u64 D0 = D[2 * l], D1 = D[2 * l + 1];
  u64 S0 = S[2 * l], S1 = S[2 * l + 1];
  u64 u0 = ~(D0 | S0), u1 = ~(D1 | S1);
  int cnt = __popcll(u0) + __popcll(u1);
  int pre = cnt;
  for (int d = 1; d < 64; d <<= 1) {
    int v = __shfl_up(pre, d);
    if (l >= d) pre += v;
  }
  int M = __shfl(pre, 63);
  int off = pre - cnt;
  {
    u64 v = u0; int o = off;
    while (v) { int b = __builtin_ctzll(v); v &= v - 1; ulist[o++] = l * 128 + b; }
    v = u1;
    while (v) { int b = __builtin_ctzll(v); v &= v - 1; ulist[o++] = l * 128 + 64 + b; }
  }
  __syncthreads();
  if (M > 0) {
    ulong2 ring[8];
    int pj[8];
#pragma unroll
    for (int q = 0; q < 8; ++q) {
      int j = ulist[q < M ? q : M - 1];
      pj[q] = j;
      ring[q] = *(const ulong2*)&mrow[(size_t)j * NT + 2 * l];
    }
    for (int m = 0; m < M; ++m) {
      int slot = m & 7;
      int j = pj[slot];
      ulong2 rv = ring[slot];
      int jt = j >> 6;
      u64 bm = (1ull << (j & 63)) - 1ull;
      u64 m0 = (2 * l < jt) ? ~0ull : ((2 * l == jt) ? bm : 0ull);
      u64 m1 = (2 * l + 1 < jt) ? ~0ull : ((2 * l + 1 == jt) ? bm : 0ull);
      bool hit = ((rv.x & D0 & m0) | (rv.y & D1 & m1)) != 0ull;
      bool head = (__ballot(hit) == 0ull);
      u64 bset = 1ull << (j & 63);
      D0 |= (head && (2 * l == jt)) ? bset : 0ull;
      D1 |= (head && (2 * l + 1 == jt)) ? bset : 0ull;
      int nm = m + 8;
      int j2 = ulist[nm < M ? nm : M - 1];
      pj[slot] = j2;
      ring[slot] = *(const ulong2*)&mrow[(size_t)j2 * NT + 2 * l];
    }
  }
  D[2 * l] = D0;
  D[2 * l + 1] = D1;
}

// ---------------------------------------------------------------------------
// K7: parallel cluster assignment + segment atomics. cluster[j] = first head
// adjacent to j (symmetry: row j == column j). Every j hits (itself if head).
// ---------------------------------------------------------------------------
__global__ __launch_bounds__(256) void k_cluster(const u64* __restrict__ mtile,
                                                 const u64* __restrict__ D,
                                                 const float* __restrict__ ss,
                                                 const float* __restrict__ by2s,
                                                 int* __restrict__ cluster,
                                                 int* __restrict__ cnt,
                                                 float* __restrict__ prob,
                                                 unsigned* __restrict__ y2m) {
  __shared__ u64 hlds[NT];
  __shared__ int red[4][64];
  int gy = blockIdx.x;
  if (threadIdx.x < NT) hlds[threadIdx.x] = D[threadIdx.x];
  __syncthreads();
  int w = threadIdx.x >> 6, r = threadIdx.x & 63;
  int best = 0x7fffffff;
  for (int kk = 0; kk < 32; ++kk) {
    int k = 32 * w + kk;
    u64 v = mtile[((size_t)gy * NT + k) * 64 + r] & hlds[k];
    if (v && best == 0x7fffffff) best = k * 64 + __builtin_ctzll(v);
  }
  red[w][r] = best;
  __syncthreads();
  if (w == 0) {
    int b = min(min(red[0][r], red[1][r]), min(red[2][r], red[3][r]));
    int j = gy * 64 + r;
    cluster[j] = b;
    atomicAdd(&cnt[b], 1);
    atomicAdd(&prob[b], ss[j]);
    atomicMax(&y2m[b], __float_as_uint(by2s[j]));
  }
}

// ---------------------------------------------------------------------------
// K8: first index achieving the cluster max y2
// ---------------------------------------------------------------------------
__global__ __launch_bounds__(256) void k_first(const int* __restrict__ cluster,
                                               const float* __restrict__ by2s,
                                               const unsigned* __restrict__ y2m,
                                               int* __restrict__ first) {
  int j = blockIdx.x * 256 + threadIdx.x;
  if (j >= N) return;
  int c = cluster[j];
  if (by2s[j] >= __uint_as_float(y2m[c])) atomicMin(&first[c], j);
}

// ---------------------------------------------------------------------------
// K9: outputs. out[j][0..4] then keep[j] appended (floats 0/1).
// ---------------------------------------------------------------------------
__global__ __launch_bounds__(256) void k_out(const int* __restrict__ cluster,
                                             const float* __restrict__ bx1s, const float* __restrict__ by1s,
                                             const float* __restrict__ bx2s, const float* __restrict__ by2s,
                                             const int* __restrict__ cnt,
                                             const float* __restrict__ prob,
                                             const int* __restrict__ first,
                                             const int* __restrict__ num_models,
                                             float* __restrict__ out) {
  int j = blockIdx.x * 256 + threadIdx.x;
  if (j >= N) return;
  int c = cluster[j];
  int nm = num_models[0];
  bool valid = (float)cnt[c] >= (float)nm / 3.0f;
  bool pick = (first[c] == j);
  bool keep = pick && valid;
  float o0 = 0.f, o1 = 0.f, o2 = 0.f, o3 = 0.f, o4 = 0.f;
  if (keep) {
    o0 = bx1s[j]; o1 = by1s[j]; o2 = bx2s[j]; o3 = by2s[j];
    o4 = prob[c] / (float)nm;
  }
  out[j * 5 + 0] = o0;
  out[j * 5 + 1] = o1;
  out[j * 5 + 2] = o2;
  out[j * 5 + 3] = o3;
  out[j * 5 + 4] = o4;
  out[N * 5 + j] = keep ? 1.0f : 0.0f;
}

// ---------------------------------------------------------------------------
extern "C" void kernel_launch(void* const* d_in, const int* in_sizes, int n_in,
                              void* d_out, int out_size, void* d_ws, size_t ws_size,
                              hipStream_t stream) {
  const float* boxes = (const float*)d_in[0];
  const float* scores = (const float*)d_in[1];
  const int* num_models = (const int*)d_in[2];
  float* out = (float*)d_out;

  char* p = (char*)d_ws;
  auto take = [&](size_t bytes) {
    char* r = p;
    p += (bytes + 255) & ~(size_t)255;
    return r;
  };
  u64* keys   = (u64*)take((size_t)N * 8);
  int* rank   = (int*)take((size_t)N * 4);
  float* bx1s = (float*)take((size_t)N * 4);
  float* by1s = (float*)take((size_t)N * 4);
  float* bx2s = (float*)take((size_t)N * 4);
  float* by2s = (float*)take((size_t)N * 4);
  float* ss   = (float*)take((size_t)N * 4);
  float* areas= (float*)take((size_t)N * 4);
  int* cluster= (int*)take((size_t)N * 4);
  int* cnt    = (int*)take((size_t)N * 4);
  float* prob = (float*)take((size_t)N * 4);
  unsigned* y2m = (unsigned*)take((size_t)N * 4);
  int* first  = (int*)take((size_t)N * 4);
  u64* D      = (u64*)take((size_t)NT * 8);           // head bitmap
  u64* S      = (u64*)take((size_t)NT * 8);           // suppressed bitmap
  u64* mtile  = (u64*)take((size_t)NT * NT * 64 * 8); // 8 MiB tiled adjacency
  u64* mrow   = (u64*)take((size_t)N * NT * 8);       // 8 MiB row-major adjacency

  k_init<<<N / 256, 256, 0, stream>>>(scores, keys, rank, cnt, prob, y2m, first, D, S);
  k_rank<<<dim3(N / 256, 8), 256, 0, stream>>>(keys, rank);
  k_scatter<<<N / 256, 256, 0, stream>>>(boxes, scores, rank, bx1s, by1s, bx2s, by2s, ss, areas);
  k_adj<<<NT * (NT + 1) / 2 / 4, 256, 0, stream>>>(bx1s, by1s, bx2s, by2s, areas, mtile, mrow);
  k_rounds<<<NT, 256, 0, stream>>>(mtile, D, S);
  k_fix<<<1, 64, 0, stream>>>(mrow, D, S);
  k_cluster<<<N / 64, 256, 0, stream>>>(mtile, D, ss, by2s, cluster, cnt, prob, y2m);
  k_first<<<N / 256, 256, 0, stream>>>(cluster, by2s, y2m, first);
  k_out<<<N / 256, 256, 0, stream>>>(cluster, bx1s, by1s, bx2s, by2s, cnt, prob, first, num_models, out);
}